// Round 2
// baseline (27234.451 us; speedup 1.0000x reference)
//
#include <hip/hip_runtime.h>
#include <stdint.h>

static constexpr int BB = 64;      // batch
static constexpr int TT = 128;     // seq
static constexpr int EE = 300;     // embed
static constexpr int HH = 1024;    // hidden
static constexpr int OUTW = 2 * HH;

static constexpr int KX  = HH + EE;    // 1324 real K
static constexpr int VK  = 1408;       // padded K = 11 * 128
static constexpr int CH  = 128;        // k-chunk per stage
static constexpr int NCH = VK / CH;    // 11
static constexpr int NB  = 256;        // persistent blocks (1/CU)
static constexpr int NT  = 512;        // threads/block
static constexpr int UPB = HH / NB;    // 4 hidden units per block
static constexpr int NR  = 3 * UPB;    // 12 rows (i,g,o per unit)
static constexpr int KPW = CH / 8;     // 16 k per wave per chunk
static constexpr int LDU = CH * BB / 2 / NT;  // 8 u64 stage-loads per thread per chunk

// ---------- gather: embsT[s][e][b] = table[inp[b][TT-1-s]][e] (time-reversed, transposed)
__global__ __launch_bounds__(256) void k_gather(const float* __restrict__ tbl,
                                                const int* __restrict__ inp,
                                                float* __restrict__ embsT) {
  __shared__ float tile[EE * 65];
  __shared__ int toks[BB];
  const int s = blockIdx.x;
  if (threadIdx.x < BB) toks[threadIdx.x] = inp[threadIdx.x * TT + (TT - 1 - s)];
  __syncthreads();
  for (int f = threadIdx.x; f < BB * EE; f += 256) {
    int b = f / EE, e = f - b * EE;
    tile[e * 65 + b] = tbl[toks[b] * EE + e];
  }
  __syncthreads();
  float* dst = embsT + s * (EE * BB);
  for (int f = threadIdx.x; f < EE * BB; f += 256) {
    int e = f >> 6, b = f & 63;
    dst[f] = tile[e * 65 + b];
  }
}

// ---------- forward direction == single cell on last token, h=c=0 (f-gate dead)
__global__ __launch_bounds__(256) void k_fwd(const float* __restrict__ Wih,
                                             const float* __restrict__ bih,
                                             const float* __restrict__ bhh,
                                             const float* __restrict__ xT,
                                             float* __restrict__ out) {
  const int g = blockIdx.x * 256 + threadIdx.x;
  const int j = g >> 6, b = g & 63;
  const float* wi = Wih + (size_t)j * EE;
  const float* wg = Wih + (size_t)(2 * HH + j) * EE;
  const float* wo = Wih + (size_t)(3 * HH + j) * EE;
  float si = 0.f, sg = 0.f, so = 0.f;
  for (int e = 0; e < EE; ++e) {
    float x = xT[e * 64 + b];
    si += x * wi[e];
    sg += x * wg[e];
    so += x * wo[e];
  }
  si += bih[j] + bhh[j];
  sg += bih[2 * HH + j] + bhh[2 * HH + j];
  so += bih[3 * HH + j] + bhh[3 * HH + j];
  float iv = 1.f / (1.f + expf(-si));
  float gv = tanhf(sg);
  float ov = 1.f / (1.f + expf(-so));
  out[b * OUTW + j] = ov * tanhf(iv * gv);
}

// ---------- persistent backward scan, fence-free MALL-coherent h exchange
__global__ __launch_bounds__(NT, 2) void k_rec(const float* __restrict__ Whh,
                                               const float* __restrict__ Wih,
                                               const float* __restrict__ bih,
                                               const float* __restrict__ bhh,
                                               const float* __restrict__ embsT,
                                               float* __restrict__ h0buf,
                                               float* __restrict__ h1buf,
                                               unsigned int* __restrict__ syncc,
                                               float* __restrict__ out) {
  __shared__ float wc[NR * VK];      // 12 rows x [Whh | Wih | 0]   (67.6 KB)
  __shared__ float vs0[CH * BB];     // staged [h;x] chunk, dbuf A  (32 KB)
  __shared__ float vs1[CH * BB];     // dbuf B                      (32 KB)
  __shared__ float gbuf[NR * BB];    // gate pre-activations        (3 KB)
  __shared__ float bias_s[NR];

  const int tid  = threadIdx.x;
  const int bk   = blockIdx.x;
  const int lane = tid & 63;
  const int w    = tid >> 6;         // wave 0..7 -> k-slice
  const int rg   = lane >> 4;        // 0..3 -> unit (3 rows: i,g,o)
  const int bg   = lane & 15;        // 0..15 -> 4 batch cols

  // weights: loaded once, reused 128 steps
  for (int f = tid; f < NR * VK; f += NT) {
    int r = f / VK, k = f - r * VK;
    int u = r / 3, gi = r - 3 * u;
    int j0 = bk * UPB + u;
    int row = (gi == 0) ? j0 : (gi == 1 ? 2 * HH + j0 : 3 * HH + j0);
    float v;
    if (k < HH)      v = Whh[(size_t)row * HH + k];
    else if (k < KX) v = Wih[(size_t)row * EE + (k - HH)];
    else             v = 0.f;
    wc[f] = v;
  }
  if (tid < NR) {
    int u = tid / 3, gi = tid - 3 * u;
    int j0 = bk * UPB + u;
    int row = (gi == 0) ? j0 : (gi == 1 ? 2 * HH + j0 : 3 * HH + j0);
    bias_s[tid] = bih[row] + bhh[row];
  }
  __syncthreads();

  const float* hcur = h0buf;   // zeroed host-side
  float*       hnxt = h1buf;

  for (int s = 0; s < TT; ++s) {
    const float* xt = embsT + (size_t)s * (EE * BB);

    uint64_t stg[LDU];
    // stage-load chunk c into regs: h via MALL-coherent atomic loads, x cached
    auto LOADC = [&](int c) {
#pragma unroll
      for (int m = 0; m < LDU; ++m) {
        int f2 = tid + NT * m;             // u64 index within chunk
        int kk = f2 >> 5, bp = f2 & 31;
        int k = c * CH + kk;
        uint64_t v;
        if (k < HH)
          v = __hip_atomic_load((const uint64_t*)hcur + (size_t)k * 32 + bp,
                                __ATOMIC_RELAXED, __HIP_MEMORY_SCOPE_AGENT);
        else if (k < KX)
          v = *((const uint64_t*)xt + (size_t)(k - HH) * 32 + bp);
        else
          v = 0ull;
        stg[m] = v;
      }
    };
    auto WRITEC = [&](float* buf) {
#pragma unroll
      for (int m = 0; m < LDU; ++m)
        ((uint64_t*)buf)[tid + NT * m] = stg[m];
    };

    LOADC(0);
    WRITEC(vs0);
    __syncthreads();

    float acc[3][4];
#pragma unroll
    for (int r3 = 0; r3 < 3; ++r3)
#pragma unroll
      for (int cc = 0; cc < 4; ++cc) acc[r3][cc] = 0.f;

    for (int c = 0; c < NCH; ++c) {
      if (c + 1 < NCH) LOADC(c + 1);       // issue next-chunk loads before compute
      const float* vb = (c & 1) ? vs1 : vs0;
      const int kb0 = c * CH + w * KPW;    // global k of this wave's slice
      const int kl0 = w * KPW;             // chunk-local
#pragma unroll
      for (int kq = 0; kq < KPW / 4; ++kq) {
        union { float4 v; float f[4]; } w0, w1, w2;
        w0.v = *(const float4*)&wc[(rg * 3 + 0) * VK + kb0 + kq * 4];
        w1.v = *(const float4*)&wc[(rg * 3 + 1) * VK + kb0 + kq * 4];
        w2.v = *(const float4*)&wc[(rg * 3 + 2) * VK + kb0 + kq * 4];
#pragma unroll
        for (int k4 = 0; k4 < 4; ++k4) {
          float4 vv = *(const float4*)&vb[(kl0 + kq * 4 + k4) * 64 + bg * 4];
          acc[0][0] = fmaf(w0.f[k4], vv.x, acc[0][0]);
          acc[0][1] = fmaf(w0.f[k4], vv.y, acc[0][1]);
          acc[0][2] = fmaf(w0.f[k4], vv.z, acc[0][2]);
          acc[0][3] = fmaf(w0.f[k4], vv.w, acc[0][3]);
          acc[1][0] = fmaf(w1.f[k4], vv.x, acc[1][0]);
          acc[1][1] = fmaf(w1.f[k4], vv.y, acc[1][1]);
          acc[1][2] = fmaf(w1.f[k4], vv.z, acc[1][2]);
          acc[1][3] = fmaf(w1.f[k4], vv.w, acc[1][3]);
          acc[2][0] = fmaf(w2.f[k4], vv.x, acc[2][0]);
          acc[2][1] = fmaf(w2.f[k4], vv.y, acc[2][1]);
          acc[2][2] = fmaf(w2.f[k4], vv.z, acc[2][2]);
          acc[2][3] = fmaf(w2.f[k4], vv.w, acc[2][3]);
        }
      }
      __syncthreads();
      if (c + 1 < NCH) {
        WRITEC((c & 1) ? vs0 : vs1);       // fill buf^1 for next chunk
        __syncthreads();
      }
    }

    // cross-wave k-slice reduction
    float* red = vs0;                      // 8*64*12*4 = 24 KB, safe to reuse
#pragma unroll
    for (int r3 = 0; r3 < 3; ++r3)
#pragma unroll
      for (int cc = 0; cc < 4; ++cc)
        red[(w * 64 + lane) * NR + r3 * 4 + cc] = acc[r3][cc];
    __syncthreads();

    for (int idx = tid; idx < NR * 64; idx += NT) {
      int r = idx >> 6, b = idx & 63;
      int lsrc = (r / 3) * 16 + (b >> 2);
      int off  = (r % 3) * 4 + (b & 3);
      float sum = bias_s[r];
#pragma unroll
      for (int w2 = 0; w2 < 8; ++w2) sum += red[(w2 * 64 + lsrc) * NR + off];
      gbuf[r * 64 + b] = sum;
    }
    __syncthreads();

    if (tid < 256) {
      int u = tid >> 6, b = tid & 63;
      float si = gbuf[(u * 3 + 0) * 64 + b];
      float sg = gbuf[(u * 3 + 1) * 64 + b];
      float so = gbuf[(u * 3 + 2) * 64 + b];
      float iv = 1.f / (1.f + expf(-si));
      float gv = tanhf(sg);
      float ov = 1.f / (1.f + expf(-so));
      float hv = ov * tanhf(iv * gv);      // c stays 0 (reference bug preserved)
      int j0 = bk * UPB + u;
      __hip_atomic_store((uint32_t*)hnxt + (size_t)j0 * 64 + b, __float_as_uint(hv),
                         __ATOMIC_RELAXED, __HIP_MEMORY_SCOPE_AGENT);
      if (s == TT - 1) out[b * OUTW + HH + j0] = hv;
    }

    { const float* t = hcur; hcur = hnxt; hnxt = (float*)t; }

    // fence-free barrier: drain own stores -> relaxed flag add -> spin
    asm volatile("s_waitcnt vmcnt(0)" ::: "memory");
    __syncthreads();
    if (tid == 0) {
      __hip_atomic_fetch_add(syncc, 1u, __ATOMIC_RELAXED, __HIP_MEMORY_SCOPE_AGENT);
      const unsigned int tgt = (unsigned int)(NB * (s + 1));
      while (__hip_atomic_load(syncc, __ATOMIC_RELAXED, __HIP_MEMORY_SCOPE_AGENT) < tgt)
        __builtin_amdgcn_s_sleep(1);
    }
    __syncthreads();
  }
}

extern "C" void kernel_launch(void* const* d_in, const int* in_sizes, int n_in,
                              void* d_out, int out_size, void* d_ws, size_t ws_size,
                              hipStream_t stream) {
  const float* tbl   = (const float*)d_in[0];
  const float* Wih_f = (const float*)d_in[1];
  // d_in[2] = Whh_f: dead (forward h is always 0)
  const float* bih_f = (const float*)d_in[3];
  const float* bhh_f = (const float*)d_in[4];
  const float* Wih_b = (const float*)d_in[5];
  const float* Whh_b = (const float*)d_in[6];
  const float* bih_b = (const float*)d_in[7];
  const float* bhh_b = (const float*)d_in[8];
  const int*   inp   = (const int*)d_in[9];
  float* out = (float*)d_out;

  char* ws = (char*)d_ws;
  unsigned int* syncc = (unsigned int*)ws;
  float* h0    = (float*)(ws + 1024);
  float* h1    = h0 + HH * BB;
  float* embsT = h1 + HH * BB;     // [128][300][64] f32 = 9.83 MB

  hipMemsetAsync(d_ws, 0, 1024 + (size_t)HH * BB * sizeof(float), stream);

  k_gather<<<dim3(TT), dim3(256), 0, stream>>>(tbl, inp, embsT);
  k_fwd<<<dim3(256), dim3(256), 0, stream>>>(Wih_f, bih_f, bhh_f, embsT, out);

  void* args[] = { (void*)&Whh_b, (void*)&Wih_b, (void*)&bih_b, (void*)&bhh_b,
                   (void*)&embsT, (void*)&h0, (void*)&h1, (void*)&syncc, (void*)&out };
  hipLaunchCooperativeKernel((void*)k_rec, dim3(NB), dim3(NT), args, 0, stream);
}

// Round 3
// 2896.374 us; speedup vs baseline: 9.4029x; 9.4029x over previous
//
#include <hip/hip_runtime.h>
#include <stdint.h>

static constexpr int BB = 64;      // batch
static constexpr int TT = 128;     // seq
static constexpr int EE = 300;     // embed
static constexpr int HH = 1024;    // hidden
static constexpr int OUTW = 2 * HH;

static constexpr int KX  = HH + EE;    // 1324 real K
static constexpr int VK  = 1408;       // padded K = 11 * 128
static constexpr int CH  = 128;        // k-chunk per stage
static constexpr int NCH = VK / CH;    // 11  (chunks 0..7 pure h, 8..10 x/pad)
static constexpr int NB  = 256;        // persistent blocks (1/CU)
static constexpr int NT  = 512;        // threads/block
static constexpr int UPB = HH / NB;    // 4 hidden units per block
static constexpr int NR  = 3 * UPB;    // 12 rows (i,g,o per unit)
static constexpr int KPW = CH / 8;     // 16 k per wave per chunk

union F4 { float4 v; float f[4]; };

// ---------- gather: embsT[s][e][b] = table[inp[b][TT-1-s]][e] (time-reversed, transposed)
__global__ __launch_bounds__(256) void k_gather(const float* __restrict__ tbl,
                                                const int* __restrict__ inp,
                                                float* __restrict__ embsT) {
  __shared__ float tile[EE * 65];
  __shared__ int toks[BB];
  const int s = blockIdx.x;
  if (threadIdx.x < BB) toks[threadIdx.x] = inp[threadIdx.x * TT + (TT - 1 - s)];
  __syncthreads();
  for (int f = threadIdx.x; f < BB * EE; f += 256) {
    int b = f / EE, e = f - b * EE;
    tile[e * 65 + b] = tbl[toks[b] * EE + e];
  }
  __syncthreads();
  float* dst = embsT + s * (EE * BB);
  for (int f = threadIdx.x; f < EE * BB; f += 256) {
    int e = f >> 6, b = f & 63;
    dst[f] = tile[e * 65 + b];
  }
}

// ---------- forward direction == single cell on last token, h=c=0 (f-gate dead)
__global__ __launch_bounds__(256) void k_fwd(const float* __restrict__ Wih,
                                             const float* __restrict__ bih,
                                             const float* __restrict__ bhh,
                                             const float* __restrict__ xT,
                                             float* __restrict__ out) {
  const int g = blockIdx.x * 256 + threadIdx.x;
  const int j = g >> 6, b = g & 63;
  const float* wi = Wih + (size_t)j * EE;
  const float* wg = Wih + (size_t)(2 * HH + j) * EE;
  const float* wo = Wih + (size_t)(3 * HH + j) * EE;
  float si = 0.f, sg = 0.f, so = 0.f;
  for (int e = 0; e < EE; ++e) {
    float x = xT[e * 64 + b];
    si += x * wi[e];
    sg += x * wg[e];
    so += x * wo[e];
  }
  si += bih[j] + bhh[j];
  sg += bih[2 * HH + j] + bhh[2 * HH + j];
  so += bih[3 * HH + j] + bhh[3 * HH + j];
  float iv = 1.f / (1.f + expf(-si));
  float gv = tanhf(sg);
  float ov = 1.f / (1.f + expf(-so));
  out[b * OUTW + j] = ov * tanhf(iv * gv);
}

// MALL-coherent helpers: sc0 sc1 = bypass L1+L2, hit the die-level coherence
// point. This replaces round-1's buffer_wbl2/inv fences (100 us/step) and
// round-2's wide-atomic CAS disaster (81 GB of HBM traffic).
__device__ __forceinline__ float4 load4_mall(const float* p) {
  float4 r;
  asm volatile("global_load_dwordx4 %0, %1, off sc0 sc1" : "=v"(r) : "v"(p));
  return r;  // NOT ready until an explicit s_waitcnt vmcnt(0)!
}

// ---------- persistent backward scan
__global__ __launch_bounds__(NT, 2) void k_rec(const float* __restrict__ Whh,
                                               const float* __restrict__ Wih,
                                               const float* __restrict__ bih,
                                               const float* __restrict__ bhh,
                                               const float* __restrict__ embsT,
                                               float* __restrict__ h0buf,
                                               float* __restrict__ h1buf,
                                               unsigned int* __restrict__ syncc,
                                               float* __restrict__ out) {
  __shared__ float wc[NR * VK];      // 12 rows x [Whh | Wih | 0]   (67.6 KB)
  __shared__ float vs0[CH * BB];     // staged [h;x] chunk, dbuf A  (32 KB)
  __shared__ float vs1[CH * BB];     // dbuf B                      (32 KB)
  __shared__ float gbuf[NR * BB];    // gate pre-activations        (3 KB)
  __shared__ float bias_s[NR];

  const int tid  = threadIdx.x;
  const int bk   = blockIdx.x;
  const int lane = tid & 63;
  const int w    = tid >> 6;         // wave 0..7 -> k-slice
  const int rg   = lane >> 4;        // 0..3 -> unit (3 rows: i,g,o)
  const int bg   = lane & 15;        // 0..15 -> 4 batch cols

  // weights: loaded once (plain cached loads), reused 128 steps
  for (int f = tid; f < NR * VK; f += NT) {
    int r = f / VK, k = f - r * VK;
    int u = r / 3, gi = r - 3 * u;
    int j0 = bk * UPB + u;
    int row = (gi == 0) ? j0 : (gi == 1 ? 2 * HH + j0 : 3 * HH + j0);
    float v;
    if (k < HH)      v = Whh[(size_t)row * HH + k];
    else if (k < KX) v = Wih[(size_t)row * EE + (k - HH)];
    else             v = 0.f;
    wc[f] = v;
  }
  if (tid < NR) {
    int u = tid / 3, gi = tid - 3 * u;
    int j0 = bk * UPB + u;
    int row = (gi == 0) ? j0 : (gi == 1 ? 2 * HH + j0 : 3 * HH + j0);
    bias_s[tid] = bih[row] + bhh[row];
  }
  __syncthreads();

  const float* hcur = h0buf;   // zeroed host-side
  float*       hnxt = h1buf;

  for (int s = 0; s < TT; ++s) {
    const float* xt = embsT + (size_t)s * (EE * BB);

    // ---- stage chunk 0 (pure h) into vs0.  vs layout [kk][b] makes each
    // chunk a contiguous 32 KB block: element offset == f*4 for f4-index f.
    {
      float4 t0 = load4_mall(hcur + (size_t)(tid       ) * 4);
      float4 t1 = load4_mall(hcur + (size_t)(tid +  512) * 4);
      float4 t2 = load4_mall(hcur + (size_t)(tid + 1024) * 4);
      float4 t3 = load4_mall(hcur + (size_t)(tid + 1536) * 4);
      asm volatile("s_waitcnt vmcnt(0)" ::: "memory");
      __builtin_amdgcn_sched_barrier(0);
      float4* d = (float4*)vs0;
      d[tid] = t0; d[tid + 512] = t1; d[tid + 1024] = t2; d[tid + 1536] = t3;
    }
    __syncthreads();

    float acc[3][4];
#pragma unroll
    for (int r3 = 0; r3 < 3; ++r3)
#pragma unroll
      for (int cc = 0; cc < 4; ++cc) acc[r3][cc] = 0.f;

    for (int c = 0; c < NCH; ++c) {
      const bool pf = (c + 1 < NCH);
      float4 t0, t1, t2, t3;
      if (pf) {
        const int cn = c + 1;
        if (cn < 8) {                        // h chunk: MALL-coherent asm loads
          const float* hb = hcur + (size_t)cn * CH * 64;
          t0 = load4_mall(hb + (size_t)(tid       ) * 4);
          t1 = load4_mall(hb + (size_t)(tid +  512) * 4);
          t2 = load4_mall(hb + (size_t)(tid + 1024) * 4);
          t3 = load4_mall(hb + (size_t)(tid + 1536) * 4);
        } else {                             // x / pad chunk: plain cached loads
          const float* xb = xt + ((size_t)(cn * CH - HH)) * 64;
          const int vlim = (KX - cn * CH) * 16;   // f4-count that is real x
          float4 z = make_float4(0.f, 0.f, 0.f, 0.f);
          t0 = (tid        < vlim) ? *(const float4*)(xb + (size_t)(tid       ) * 4) : z;
          t1 = (tid +  512 < vlim) ? *(const float4*)(xb + (size_t)(tid +  512) * 4) : z;
          t2 = (tid + 1024 < vlim) ? *(const float4*)(xb + (size_t)(tid + 1024) * 4) : z;
          t3 = (tid + 1536 < vlim) ? *(const float4*)(xb + (size_t)(tid + 1536) * 4) : z;
        }
      }

      // ---- compute on current buffer
      const float* vb = (c & 1) ? vs1 : vs0;
      const int kb0 = c * CH + w * KPW;
      const int kl0 = w * KPW;
#pragma unroll
      for (int kq = 0; kq < KPW / 4; ++kq) {
        F4 w0, w1, w2;
        w0.v = *(const float4*)&wc[(rg * 3 + 0) * VK + kb0 + kq * 4];
        w1.v = *(const float4*)&wc[(rg * 3 + 1) * VK + kb0 + kq * 4];
        w2.v = *(const float4*)&wc[(rg * 3 + 2) * VK + kb0 + kq * 4];
#pragma unroll
        for (int k4 = 0; k4 < 4; ++k4) {
          float4 vv = *(const float4*)&vb[(kl0 + kq * 4 + k4) * 64 + bg * 4];
          acc[0][0] = fmaf(w0.f[k4], vv.x, acc[0][0]);
          acc[0][1] = fmaf(w0.f[k4], vv.y, acc[0][1]);
          acc[0][2] = fmaf(w0.f[k4], vv.z, acc[0][2]);
          acc[0][3] = fmaf(w0.f[k4], vv.w, acc[0][3]);
          acc[1][0] = fmaf(w1.f[k4], vv.x, acc[1][0]);
          acc[1][1] = fmaf(w1.f[k4], vv.y, acc[1][1]);
          acc[1][2] = fmaf(w1.f[k4], vv.z, acc[1][2]);
          acc[1][3] = fmaf(w1.f[k4], vv.w, acc[1][3]);
          acc[2][0] = fmaf(w2.f[k4], vv.x, acc[2][0]);
          acc[2][1] = fmaf(w2.f[k4], vv.y, acc[2][1]);
          acc[2][2] = fmaf(w2.f[k4], vv.z, acc[2][2]);
          acc[2][3] = fmaf(w2.f[k4], vv.w, acc[2][3]);
        }
      }
      __syncthreads();

      if (pf) {
        if (c + 1 < 8) {                     // asm loads need explicit drain
          asm volatile("s_waitcnt vmcnt(0)" ::: "memory");
          __builtin_amdgcn_sched_barrier(0);
        }                                    // (plain loads: compiler waits)
        float4* d = (float4*)((c & 1) ? vs0 : vs1);
        d[tid] = t0; d[tid + 512] = t1; d[tid + 1024] = t2; d[tid + 1536] = t3;
        __syncthreads();
      }
    }

    // cross-wave k-slice reduction (reuse vs0; all compute reads are done)
    float* red = vs0;
#pragma unroll
    for (int r3 = 0; r3 < 3; ++r3)
#pragma unroll
      for (int cc = 0; cc < 4; ++cc)
        red[(w * 64 + lane) * NR + r3 * 4 + cc] = acc[r3][cc];
    __syncthreads();

    for (int idx = tid; idx < NR * 64; idx += NT) {
      int r = idx >> 6, b = idx & 63;
      int lsrc = (r / 3) * 16 + (b >> 2);
      int off  = (r % 3) * 4 + (b & 3);
      float sum = bias_s[r];
#pragma unroll
      for (int w2 = 0; w2 < 8; ++w2) sum += red[(w2 * 64 + lsrc) * NR + off];
      gbuf[r * 64 + b] = sum;
    }
    __syncthreads();

    if (tid < 256) {
      int u = tid >> 6, b = tid & 63;
      float si = gbuf[(u * 3 + 0) * 64 + b];
      float sg = gbuf[(u * 3 + 1) * 64 + b];
      float so = gbuf[(u * 3 + 2) * 64 + b];
      float iv = 1.f / (1.f + expf(-si));
      float gv = tanhf(sg);
      float ov = 1.f / (1.f + expf(-so));
      float hv = ov * tanhf(iv * gv);        // c stays 0 (reference bug preserved)
      int j0 = bk * UPB + u;
      const float* dst = hnxt + (size_t)j0 * 64 + b;
      asm volatile("global_store_dword %0, %1, off sc0 sc1"
                   :: "v"(dst), "v"(hv) : "memory");   // write-through to MALL
      if (s == TT - 1) out[b * OUTW + HH + j0] = hv;
    }

    { const float* t = hcur; hcur = hnxt; hnxt = (float*)t; }

    // barrier: per-wave store drain -> one atomicAdd/block -> sc-flagged spin
    asm volatile("s_waitcnt vmcnt(0)" ::: "memory");
    __syncthreads();
    if (tid == 0) {
      atomicAdd(syncc, 1u);                  // device-scope, executes at MALL
      const unsigned int tgt = (unsigned int)(NB * (s + 1));
      unsigned int cur;
      do {
        __builtin_amdgcn_s_sleep(2);
        asm volatile("global_load_dword %0, %1, off sc0 sc1\n\t"
                     "s_waitcnt vmcnt(0)"
                     : "=v"(cur) : "v"(syncc) : "memory");
      } while (cur < tgt);
    }
    __syncthreads();
  }
}

extern "C" void kernel_launch(void* const* d_in, const int* in_sizes, int n_in,
                              void* d_out, int out_size, void* d_ws, size_t ws_size,
                              hipStream_t stream) {
  const float* tbl   = (const float*)d_in[0];
  const float* Wih_f = (const float*)d_in[1];
  // d_in[2] = Whh_f: dead (forward h is always 0)
  const float* bih_f = (const float*)d_in[3];
  const float* bhh_f = (const float*)d_in[4];
  const float* Wih_b = (const float*)d_in[5];
  const float* Whh_b = (const float*)d_in[6];
  const float* bih_b = (const float*)d_in[7];
  const float* bhh_b = (const float*)d_in[8];
  const int*   inp   = (const int*)d_in[9];
  float* out = (float*)d_out;

  char* ws = (char*)d_ws;
  unsigned int* syncc = (unsigned int*)ws;
  float* h0    = (float*)(ws + 1024);
  float* h1    = h0 + HH * BB;
  float* embsT = h1 + HH * BB;     // [128][300][64] f32 = 9.83 MB

  hipMemsetAsync(d_ws, 0, 1024 + (size_t)HH * BB * sizeof(float), stream);

  k_gather<<<dim3(TT), dim3(256), 0, stream>>>(tbl, inp, embsT);
  k_fwd<<<dim3(256), dim3(256), 0, stream>>>(Wih_f, bih_f, bhh_f, embsT, out);

  void* args[] = { (void*)&Whh_b, (void*)&Wih_b, (void*)&bih_b, (void*)&bhh_b,
                   (void*)&embsT, (void*)&h0, (void*)&h1, (void*)&syncc, (void*)&out };
  hipLaunchCooperativeKernel((void*)k_rec, dim3(NB), dim3(NT), args, 0, stream);
}

// Round 5
// 2760.709 us; speedup vs baseline: 9.8650x; 1.0491x over previous
//
#include <hip/hip_runtime.h>
#include <stdint.h>

static constexpr int BB = 64;      // batch
static constexpr int TT = 128;     // seq
static constexpr int EE = 300;     // embed
static constexpr int HH = 1024;    // hidden
static constexpr int OUTW = 2 * HH;
static constexpr int NB  = 256;    // persistent blocks (1/CU)
static constexpr int NT  = 512;    // threads/block

// K-dim: concat [h(1024) | x(300) | pad..1408) ] = 44 kb-blocks of 32.
// kb 0..31 = h (exchanged buffer), kb 32..43 = x (precomputed per step).
// Element (k, col) lives at byte: kb*8192 + col*128 + (hilo*4 + ksub)*16 + (k&7)*2
// where kb=k>>5, ksub=(k>>3)&3.  hi-plane hilo=0, lo-plane hilo=1. bf16 RNE.

typedef __attribute__((ext_vector_type(8))) short bf16x8;
typedef __attribute__((ext_vector_type(4))) float f32x4;
union U16 { uint4 u; bf16x8 v; };

__device__ __forceinline__ unsigned short f2bf(float f) {
  uint32_t u = __float_as_uint(f);
  uint32_t r = (u + 0x7fffu + ((u >> 16) & 1u)) >> 16;
  return (unsigned short)r;
}
__device__ __forceinline__ float bf2f(unsigned short h) {
  return __uint_as_float(((uint32_t)h) << 16);
}

__device__ __forceinline__ void gload16_sc(uint4& d, const void* p) {
  asm volatile("global_load_dwordx4 %0, %1, off sc0 sc1" : "=v"(d) : "v"(p));
}
__device__ __forceinline__ void gload16_nc(uint4& d, const void* p) {
  asm volatile("global_load_dwordx4 %0, %1, off" : "=v"(d) : "v"(p));
}

// ---------- stage: token gather -> xfrag (bf16 hi/lo, frag layout, time-reversed)
//            + xT0 (fp32 [300][64] of s=0, for k_fwd)
__global__ __launch_bounds__(256) void k_stage(const float* __restrict__ tbl,
                                               const int* __restrict__ inp,
                                               unsigned char* __restrict__ xfrag,
                                               float* __restrict__ xT0) {
  __shared__ float tile[EE * 65];
  __shared__ int toks[BB];
  const int s = blockIdx.x;
  const int tid = threadIdx.x;
  if (tid < BB) toks[tid] = inp[tid * TT + (TT - 1 - s)];
  __syncthreads();
  for (int f = tid; f < BB * EE; f += 256) {
    int b = f / EE, e = f - b * EE;
    tile[e * 65 + b] = tbl[(size_t)toks[b] * EE + e];
  }
  __syncthreads();
  if (s == 0) {
    for (int f = tid; f < EE * BB; f += 256) {
      int e = f >> 6, b = f & 63;
      xT0[f] = tile[e * 65 + b];
    }
  }
  const int ksub = tid & 3, col = (tid >> 2) & 63;
  unsigned char* base = xfrag + (size_t)s * 98304;
  for (int kb = 0; kb < 12; ++kb) {
    uint32_t hi[4], lo[4];
#pragma unroll
    for (int j2 = 0; j2 < 4; ++j2) {
      int e0 = kb * 32 + ksub * 8 + 2 * j2;
      float f0 = (e0     < EE) ? tile[e0 * 65 + col]      : 0.f;
      float f1 = (e0 + 1 < EE) ? tile[(e0 + 1) * 65 + col] : 0.f;
      unsigned short h0 = f2bf(f0), h1 = f2bf(f1);
      unsigned short l0 = f2bf(f0 - bf2f(h0)), l1 = f2bf(f1 - bf2f(h1));
      hi[j2] = (uint32_t)h0 | ((uint32_t)h1 << 16);
      lo[j2] = (uint32_t)l0 | ((uint32_t)l1 << 16);
    }
    unsigned char* p = base + kb * 8192 + col * 128 + ksub * 16;
    *(uint4*)p        = make_uint4(hi[0], hi[1], hi[2], hi[3]);
    *(uint4*)(p + 64) = make_uint4(lo[0], lo[1], lo[2], lo[3]);
  }
}

// ---------- forward direction == single cell on last token, h=c=0 (f-gate dead)
__global__ __launch_bounds__(256) void k_fwd(const float* __restrict__ Wih,
                                             const float* __restrict__ bih,
                                             const float* __restrict__ bhh,
                                             const float* __restrict__ xT,
                                             float* __restrict__ out) {
  const int g = blockIdx.x * 256 + threadIdx.x;
  const int j = g >> 6, b = g & 63;
  const float* wi = Wih + (size_t)j * EE;
  const float* wg = Wih + (size_t)(2 * HH + j) * EE;
  const float* wo = Wih + (size_t)(3 * HH + j) * EE;
  float si = 0.f, sg = 0.f, so = 0.f;
  for (int e = 0; e < EE; ++e) {
    float x = xT[e * 64 + b];
    si += x * wi[e];
    sg += x * wg[e];
    so += x * wo[e];
  }
  si += bih[j] + bhh[j];
  sg += bih[2 * HH + j] + bhh[2 * HH + j];
  so += bih[3 * HH + j] + bhh[3 * HH + j];
  float iv = 1.f / (1.f + expf(-si));
  float gv = tanhf(sg);
  float ov = 1.f / (1.f + expf(-so));
  out[b * OUTW + j] = ov * tanhf(iv * gv);
}

// ---------- persistent backward scan: MFMA bf16 hi/lo, A in regs, B direct-global
__global__ __launch_bounds__(NT, 2) void k_rec(const float* __restrict__ Whh,
                                               const float* __restrict__ Wih,
                                               const float* __restrict__ bih,
                                               const float* __restrict__ bhh,
                                               const unsigned char* __restrict__ xfrag,
                                               unsigned char* __restrict__ h0ex,
                                               unsigned char* __restrict__ h1ex,
                                               unsigned int* __restrict__ syncc,
                                               float* __restrict__ out) {
  __shared__ float red[4 * 4 * 16 * 16];   // [w2][tile][row16][col16]  16 KB
  __shared__ float bias_s[12];

  const int tid  = threadIdx.x;
  const int bk   = blockIdx.x;
  const int lane = tid & 63;
  const int wv   = tid >> 6;
  const int w2   = wv >> 1;         // K-group 0..3 (kb ≡ w2 mod 4)
  const int nh   = wv & 1;          // N-half (cols nh*32 .. +31)
  const int l15  = lane & 15;
  const int l4   = lane >> 4;       // ksub
  const int j0   = bk * 4;          // this block's 4 hidden units

  if (tid < 12) {
    int u = tid / 3, gi = tid % 3;
    int grow = j0 + u + (gi == 0 ? 0 : (gi == 1 ? 2 * HH : 3 * HH));
    bias_s[tid] = bih[grow] + bhh[grow];
  }

  // ---- A fragments (weights) in registers, hi/lo, for all 128 steps.
  // A-frag lane map (16x16x32): row = lane&15, k = (lane>>4)*8 + j.
  bf16x8 Ah[11], Al[11];
  {
    const int row = l15;
    const bool rv = row < 12;
    const int u = rv ? row / 3 : 0, gi = rv ? row % 3 : 0;
    const int grow = j0 + u + (gi == 0 ? 0 : (gi == 1 ? 2 * HH : 3 * HH));
#pragma unroll
    for (int c = 0; c < 11; ++c) {
      const int kb = w2 + 4 * c;
      const int k0 = kb * 32 + l4 * 8;
      U16 ah, al;
      // NOTE: all 4 dwords of ah/al are written below; round-4 bug was an
      // `ah.u.x = 0` INSIDE this loop that re-zeroed dword 0 every iteration.
#pragma unroll
      for (int j2 = 0; j2 < 4; ++j2) {
        float f0 = 0.f, f1 = 0.f;
        if (rv) {
          int k = k0 + 2 * j2;
          if (k < HH) {
            f0 = Whh[(size_t)grow * HH + k];
            f1 = Whh[(size_t)grow * HH + k + 1];
          } else {
            int e = k - HH;
            if (e     < EE) f0 = Wih[(size_t)grow * EE + e];
            if (e + 1 < EE) f1 = Wih[(size_t)grow * EE + e + 1];
          }
        }
        unsigned short h0 = f2bf(f0), h1 = f2bf(f1);
        unsigned short q0 = f2bf(f0 - bf2f(h0)), q1 = f2bf(f1 - bf2f(h1));
        ((uint32_t*)&ah.u)[j2] = (uint32_t)h0 | ((uint32_t)h1 << 16);
        ((uint32_t*)&al.u)[j2] = (uint32_t)q0 | ((uint32_t)q1 << 16);
      }
      Ah[c] = ah.v;
      Al[c] = al.v;
    }
  }
  __syncthreads();

  // per-lane byte offsets within one kb-block, per (tile, hi/lo)
  const uint32_t c0h = (uint32_t)((nh * 32 + l15) * 128 + l4 * 16);
  const uint32_t c0l = c0h + 64;
  const uint32_t c1h = c0h + 16 * 128;
  const uint32_t c1l = c1h + 64;

  for (int s = 0; s < TT; ++s) {
    const unsigned char* hb = (s & 1) ? h1ex : h0ex;   // read
    unsigned char*       hn = (s & 1) ? h0ex : h1ex;   // write
    const unsigned char* xb = xfrag + (size_t)s * 98304;
    const unsigned char* hbase = hb + w2 * 8192;
    const unsigned char* xbase = xb + w2 * 8192;

    uint4 pb[2][4];
    // prologue: issue c=0 (h-part)
    gload16_sc(pb[0][0], hbase + c0h);
    gload16_sc(pb[0][1], hbase + c0l);
    gload16_sc(pb[0][2], hbase + c1h);
    gload16_sc(pb[0][3], hbase + c1l);

    f32x4 acc0 = {0.f, 0.f, 0.f, 0.f};
    f32x4 acc1 = {0.f, 0.f, 0.f, 0.f};

#pragma unroll
    for (int c = 0; c < 11; ++c) {
      if (c < 10) {                       // issue c+1
        const int cn = c + 1;
        if (cn < 8) {
          const unsigned char* p = hbase + (size_t)cn * 32768;
          gload16_sc(pb[cn & 1][0], p + c0h);
          gload16_sc(pb[cn & 1][1], p + c0l);
          gload16_sc(pb[cn & 1][2], p + c1h);
          gload16_sc(pb[cn & 1][3], p + c1l);
        } else {
          const unsigned char* p = xbase + (size_t)(cn - 8) * 32768;
          gload16_nc(pb[cn & 1][0], p + c0h);
          gload16_nc(pb[cn & 1][1], p + c0l);
          gload16_nc(pb[cn & 1][2], p + c1h);
          gload16_nc(pb[cn & 1][3], p + c1l);
        }
        asm volatile("s_waitcnt vmcnt(4)" ::: "memory");
      } else {
        asm volatile("s_waitcnt vmcnt(0)" ::: "memory");
      }
      __builtin_amdgcn_sched_barrier(0);

      U16 t0, t1, t2, t3;
      t0.u = pb[c & 1][0]; t1.u = pb[c & 1][1];
      t2.u = pb[c & 1][2]; t3.u = pb[c & 1][3];
      // acc += Ah*Bh + Al*Bh + Ah*Bl   (drop lo*lo)
      acc0 = __builtin_amdgcn_mfma_f32_16x16x32_bf16(Ah[c], t0.v, acc0, 0, 0, 0);
      acc1 = __builtin_amdgcn_mfma_f32_16x16x32_bf16(Ah[c], t2.v, acc1, 0, 0, 0);
      acc0 = __builtin_amdgcn_mfma_f32_16x16x32_bf16(Al[c], t0.v, acc0, 0, 0, 0);
      acc1 = __builtin_amdgcn_mfma_f32_16x16x32_bf16(Al[c], t2.v, acc1, 0, 0, 0);
      acc0 = __builtin_amdgcn_mfma_f32_16x16x32_bf16(Ah[c], t1.v, acc0, 0, 0, 0);
      acc1 = __builtin_amdgcn_mfma_f32_16x16x32_bf16(Ah[c], t3.v, acc1, 0, 0, 0);
    }

    // ---- epilogue: D-frag (col=lane&15, row=(lane>>4)*4+r) -> LDS reduce
#pragma unroll
    for (int r = 0; r < 4; ++r) {
      red[(((w2 * 4) + (nh * 2 + 0)) * 16 + (l4 * 4 + r)) * 16 + l15] = acc0[r];
      red[(((w2 * 4) + (nh * 2 + 1)) * 16 + (l4 * 4 + r)) * 16 + l15] = acc1[r];
    }
    __syncthreads();

    if (tid < 256) {
      const int u = tid >> 6, b = tid & 63;
      const int t = b >> 4, c16 = b & 15;
      float g3[3];
#pragma unroll
      for (int gi = 0; gi < 3; ++gi) {
        const int row = u * 3 + gi;
        float sum = bias_s[row];
#pragma unroll
        for (int ww = 0; ww < 4; ++ww)
          sum += red[((ww * 4 + t) * 16 + row) * 16 + c16];
        g3[gi] = sum;
      }
      float iv = 1.f / (1.f + expf(-g3[0]));
      float gv = tanhf(g3[1]);
      float ov = 1.f / (1.f + expf(-g3[2]));
      float hv = ov * tanhf(iv * gv);      // c stays 0 (reference bug preserved)

      const int k = j0 + u;                // h's k-index in the B matrix
      const int kb = k >> 5, ks = (k >> 3) & 3, jj = k & 7;
      unsigned char* dh = hn + kb * 8192 + b * 128 + ks * 16 + jj * 2;
      unsigned short hhv = f2bf(hv);
      unsigned short llv = f2bf(hv - bf2f(hhv));
      asm volatile("global_store_short %0, %1, off sc0 sc1"
                   :: "v"(dh), "v"((uint32_t)hhv) : "memory");
      asm volatile("global_store_short %0, %1, off sc0 sc1"
                   :: "v"(dh + 64), "v"((uint32_t)llv) : "memory");
      if (s == TT - 1) out[b * OUTW + HH + k] = hv;
    }

    // ---- fence-free device barrier (validated round 3)
    asm volatile("s_waitcnt vmcnt(0)" ::: "memory");
    __syncthreads();
    if (tid == 0) {
      atomicAdd(syncc, 1u);
      const unsigned int tgt = (unsigned int)(NB * (s + 1));
      unsigned int cur;
      do {
        __builtin_amdgcn_s_sleep(1);
        asm volatile("global_load_dword %0, %1, off sc0 sc1\n\t"
                     "s_waitcnt vmcnt(0)"
                     : "=v"(cur) : "v"(syncc) : "memory");
      } while (cur < tgt);
    }
    __syncthreads();
  }
}

extern "C" void kernel_launch(void* const* d_in, const int* in_sizes, int n_in,
                              void* d_out, int out_size, void* d_ws, size_t ws_size,
                              hipStream_t stream) {
  const float* tbl   = (const float*)d_in[0];
  const float* Wih_f = (const float*)d_in[1];
  // d_in[2] = Whh_f: dead (forward h is always 0)
  const float* bih_f = (const float*)d_in[3];
  const float* bhh_f = (const float*)d_in[4];
  const float* Wih_b = (const float*)d_in[5];
  const float* Whh_b = (const float*)d_in[6];
  const float* bih_b = (const float*)d_in[7];
  const float* bhh_b = (const float*)d_in[8];
  const int*   inp   = (const int*)d_in[9];
  float* out = (float*)d_out;

  char* ws = (char*)d_ws;
  unsigned int*  syncc = (unsigned int*)ws;                  // 1 KB
  unsigned char* h0ex  = (unsigned char*)(ws + 1024);        // 256 KB
  unsigned char* h1ex  = h0ex + 262144;                      // 256 KB
  float*         xT0   = (float*)(h1ex + 262144);            // 76.8 KB
  unsigned char* xfrag = (unsigned char*)(ws + 602112);      // 12.58 MB

  // zero sync counter + initial h (hi/lo of 0 are 0)
  hipMemsetAsync(d_ws, 0, 1024 + 262144, stream);

  k_stage<<<dim3(TT), dim3(256), 0, stream>>>(tbl, inp, xfrag, xT0);
  k_fwd<<<dim3(256), dim3(256), 0, stream>>>(Wih_f, bih_f, bhh_f, xT0, out);

  void* args[] = { (void*)&Whh_b, (void*)&Wih_b, (void*)&bih_b, (void*)&bhh_b,
                   (void*)&xfrag, (void*)&h0ex, (void*)&h1ex, (void*)&syncc, (void*)&out };
  hipLaunchCooperativeKernel((void*)k_rec, dim3(NB), dim3(NT), args, 0, stream);
}

// Round 6
// 2243.066 us; speedup vs baseline: 12.1416x; 1.2308x over previous
//
#include <hip/hip_runtime.h>
#include <stdint.h>

static constexpr int BB = 64;      // batch
static constexpr int TT = 128;     // seq
static constexpr int EE = 300;     // embed
static constexpr int HH = 1024;    // hidden
static constexpr int OUTW = 2 * HH;
static constexpr int NB  = 256;    // persistent blocks (1/CU)
static constexpr int NT  = 512;    // threads/block

// K-dim: concat [h(1024) | x(300) | pad..1408) ] = 44 kb-blocks of 32.
// kb 0..31 = h (exchanged buffer), kb 32..43 = x (precomputed per step).
// Element (k, col) lives at byte: kb*8192 + col*128 + (hilo*4 + ksub)*16 + (k&7)*2
// where kb=k>>5, ksub=(k>>3)&3.  hi-plane hilo=0, lo-plane hilo=1. bf16 RNE.

typedef __attribute__((ext_vector_type(8))) short bf16x8;
typedef __attribute__((ext_vector_type(4))) float f32x4;
union U16 { uint4 u; bf16x8 v; };

__device__ __forceinline__ unsigned short f2bf(float f) {
  uint32_t u = __float_as_uint(f);
  uint32_t r = (u + 0x7fffu + ((u >> 16) & 1u)) >> 16;
  return (unsigned short)r;
}
__device__ __forceinline__ float bf2f(unsigned short h) {
  return __uint_as_float(((uint32_t)h) << 16);
}

__device__ __forceinline__ void gload16_sc(uint4& d, const void* p) {
  asm volatile("global_load_dwordx4 %0, %1, off sc0 sc1" : "=v"(d) : "v"(p));
}
__device__ __forceinline__ void gload16_nc(uint4& d, const void* p) {
  asm volatile("global_load_dwordx4 %0, %1, off" : "=v"(d) : "v"(p));
}

// ---------- stage: token gather -> xfrag (bf16 hi/lo, frag layout, time-reversed)
//            + xT0 (fp32 [300][64] of s=0, for k_fwd)
__global__ __launch_bounds__(256) void k_stage(const float* __restrict__ tbl,
                                               const int* __restrict__ inp,
                                               unsigned char* __restrict__ xfrag,
                                               float* __restrict__ xT0) {
  __shared__ float tile[EE * 65];
  __shared__ int toks[BB];
  const int s = blockIdx.x;
  const int tid = threadIdx.x;
  if (tid < BB) toks[tid] = inp[tid * TT + (TT - 1 - s)];
  __syncthreads();
  for (int f = tid; f < BB * EE; f += 256) {
    int b = f / EE, e = f - b * EE;
    tile[e * 65 + b] = tbl[(size_t)toks[b] * EE + e];
  }
  __syncthreads();
  if (s == 0) {
    for (int f = tid; f < EE * BB; f += 256) {
      int e = f >> 6, b = f & 63;
      xT0[f] = tile[e * 65 + b];
    }
  }
  const int ksub = tid & 3, col = (tid >> 2) & 63;
  unsigned char* base = xfrag + (size_t)s * 98304;
  for (int kb = 0; kb < 12; ++kb) {
    uint32_t hi[4], lo[4];
#pragma unroll
    for (int j2 = 0; j2 < 4; ++j2) {
      int e0 = kb * 32 + ksub * 8 + 2 * j2;
      float f0 = (e0     < EE) ? tile[e0 * 65 + col]      : 0.f;
      float f1 = (e0 + 1 < EE) ? tile[(e0 + 1) * 65 + col] : 0.f;
      unsigned short h0 = f2bf(f0), h1 = f2bf(f1);
      unsigned short l0 = f2bf(f0 - bf2f(h0)), l1 = f2bf(f1 - bf2f(h1));
      hi[j2] = (uint32_t)h0 | ((uint32_t)h1 << 16);
      lo[j2] = (uint32_t)l0 | ((uint32_t)l1 << 16);
    }
    unsigned char* p = base + kb * 8192 + col * 128 + ksub * 16;
    *(uint4*)p        = make_uint4(hi[0], hi[1], hi[2], hi[3]);
    *(uint4*)(p + 64) = make_uint4(lo[0], lo[1], lo[2], lo[3]);
  }
}

// ---------- forward direction == single cell on last token, h=c=0 (f-gate dead)
__global__ __launch_bounds__(256) void k_fwd(const float* __restrict__ Wih,
                                             const float* __restrict__ bih,
                                             const float* __restrict__ bhh,
                                             const float* __restrict__ xT,
                                             float* __restrict__ out) {
  const int g = blockIdx.x * 256 + threadIdx.x;
  const int j = g >> 6, b = g & 63;
  const float* wi = Wih + (size_t)j * EE;
  const float* wg = Wih + (size_t)(2 * HH + j) * EE;
  const float* wo = Wih + (size_t)(3 * HH + j) * EE;
  float si = 0.f, sg = 0.f, so = 0.f;
  for (int e = 0; e < EE; ++e) {
    float x = xT[e * 64 + b];
    si += x * wi[e];
    sg += x * wg[e];
    so += x * wo[e];
  }
  si += bih[j] + bhh[j];
  sg += bih[2 * HH + j] + bhh[2 * HH + j];
  so += bih[3 * HH + j] + bhh[3 * HH + j];
  float iv = 1.f / (1.f + expf(-si));
  float gv = tanhf(sg);
  float ov = 1.f / (1.f + expf(-so));
  out[b * OUTW + j] = ov * tanhf(iv * gv);
}

// ---------- persistent backward scan: MFMA bf16 hi/lo, A in regs, B direct-global
__global__ __launch_bounds__(NT, 2) void k_rec(const float* __restrict__ Whh,
                                               const float* __restrict__ Wih,
                                               const float* __restrict__ bih,
                                               const float* __restrict__ bhh,
                                               const unsigned char* __restrict__ xfrag,
                                               unsigned char* __restrict__ h0ex,
                                               unsigned char* __restrict__ h1ex,
                                               unsigned int* __restrict__ arr,
                                               float* __restrict__ out) {
  __shared__ float red[4 * 4 * 16 * 16];   // [w2][tile][row16][col16]  16 KB
  __shared__ float bias_s[12];

  const int tid  = threadIdx.x;
  const int bk   = blockIdx.x;
  const int lane = tid & 63;
  const int wv   = tid >> 6;
  const int w2   = wv >> 1;         // K-group 0..3 (kb ≡ w2 mod 4)
  const int nh   = wv & 1;          // N-half (cols nh*32 .. +31)
  const int l15  = lane & 15;
  const int l4   = lane >> 4;       // ksub
  const int j0   = bk * 4;          // this block's 4 hidden units

  if (tid < 12) {
    int u = tid / 3, gi = tid % 3;
    int grow = j0 + u + (gi == 0 ? 0 : (gi == 1 ? 2 * HH : 3 * HH));
    bias_s[tid] = bih[grow] + bhh[grow];
  }

  // ---- A fragments (weights) in registers, hi/lo, for all 128 steps.
  // A-frag lane map (16x16x32): row = lane&15, k = (lane>>4)*8 + j.
  bf16x8 Ah[11], Al[11];
  {
    const int row = l15;
    const bool rv = row < 12;
    const int u = rv ? row / 3 : 0, gi = rv ? row % 3 : 0;
    const int grow = j0 + u + (gi == 0 ? 0 : (gi == 1 ? 2 * HH : 3 * HH));
#pragma unroll
    for (int c = 0; c < 11; ++c) {
      const int kb = w2 + 4 * c;
      const int k0 = kb * 32 + l4 * 8;
      U16 ah, al;
#pragma unroll
      for (int j2 = 0; j2 < 4; ++j2) {
        float f0 = 0.f, f1 = 0.f;
        if (rv) {
          int k = k0 + 2 * j2;
          if (k < HH) {
            f0 = Whh[(size_t)grow * HH + k];
            f1 = Whh[(size_t)grow * HH + k + 1];
          } else {
            int e = k - HH;
            if (e     < EE) f0 = Wih[(size_t)grow * EE + e];
            if (e + 1 < EE) f1 = Wih[(size_t)grow * EE + e + 1];
          }
        }
        unsigned short h0 = f2bf(f0), h1 = f2bf(f1);
        unsigned short q0 = f2bf(f0 - bf2f(h0)), q1 = f2bf(f1 - bf2f(h1));
        ((uint32_t*)&ah.u)[j2] = (uint32_t)h0 | ((uint32_t)h1 << 16);
        ((uint32_t*)&al.u)[j2] = (uint32_t)q0 | ((uint32_t)q1 << 16);
      }
      Ah[c] = ah.v;
      Al[c] = al.v;
    }
  }
  __syncthreads();

  // per-lane byte offsets within one kb-block, per (tile, hi/lo)
  const uint32_t c0h = (uint32_t)((nh * 32 + l15) * 128 + l4 * 16);
  const uint32_t c0l = c0h + 64;
  const uint32_t c1h = c0h + 16 * 128;
  const uint32_t c1l = c1h + 64;

#define ISSUE_H(cn)                                               \
  { const unsigned char* p_ = hbase + (size_t)(cn) * 32768;       \
    gload16_sc(pb[(cn) & 3][0], p_ + c0h);                        \
    gload16_sc(pb[(cn) & 3][1], p_ + c0l);                        \
    gload16_sc(pb[(cn) & 3][2], p_ + c1h);                        \
    gload16_sc(pb[(cn) & 3][3], p_ + c1l); }
#define ISSUE_X(cn)                                               \
  { const unsigned char* p_ = xbase + (size_t)((cn) - 8) * 32768; \
    gload16_nc(pb[(cn) & 3][0], p_ + c0h);                        \
    gload16_nc(pb[(cn) & 3][1], p_ + c0l);                        \
    gload16_nc(pb[(cn) & 3][2], p_ + c1h);                        \
    gload16_nc(pb[(cn) & 3][3], p_ + c1l); }
#define ISSUE(cn) { if ((cn) < 8) ISSUE_H(cn) else ISSUE_X(cn) }

  for (int s = 0; s < TT; ++s) {
    const unsigned char* hb = (s & 1) ? h1ex : h0ex;   // read
    unsigned char*       hn = (s & 1) ? h0ex : h1ex;   // write
    const unsigned char* xb = xfrag + (size_t)s * 98304;
    const unsigned char* hbase = hb + w2 * 8192;
    const unsigned char* xbase = xb + w2 * 8192;

    uint4 pb[4][4];
    // prologue: 3-deep prefetch (chunks 0,1,2)
    ISSUE(0); ISSUE(1); ISSUE(2);

    f32x4 acc0 = {0.f, 0.f, 0.f, 0.f};
    f32x4 acc1 = {0.f, 0.f, 0.f, 0.f};

#pragma unroll
    for (int c = 0; c < 11; ++c) {
      if (c + 3 < 11) {
        ISSUE(c + 3);
        asm volatile("s_waitcnt vmcnt(12)" ::: "memory");
      } else if (c == 8) {
        asm volatile("s_waitcnt vmcnt(8)" ::: "memory");
      } else if (c == 9) {
        asm volatile("s_waitcnt vmcnt(4)" ::: "memory");
      } else {
        asm volatile("s_waitcnt vmcnt(0)" ::: "memory");
      }
      __builtin_amdgcn_sched_barrier(0);

      U16 t0, t1, t2, t3;
      t0.u = pb[c & 3][0]; t1.u = pb[c & 3][1];
      t2.u = pb[c & 3][2]; t3.u = pb[c & 3][3];
      // acc += Ah*Bh + Al*Bh + Ah*Bl   (drop lo*lo)
      acc0 = __builtin_amdgcn_mfma_f32_16x16x32_bf16(Ah[c], t0.v, acc0, 0, 0, 0);
      acc1 = __builtin_amdgcn_mfma_f32_16x16x32_bf16(Ah[c], t2.v, acc1, 0, 0, 0);
      acc0 = __builtin_amdgcn_mfma_f32_16x16x32_bf16(Al[c], t0.v, acc0, 0, 0, 0);
      acc1 = __builtin_amdgcn_mfma_f32_16x16x32_bf16(Al[c], t2.v, acc1, 0, 0, 0);
      acc0 = __builtin_amdgcn_mfma_f32_16x16x32_bf16(Ah[c], t1.v, acc0, 0, 0, 0);
      acc1 = __builtin_amdgcn_mfma_f32_16x16x32_bf16(Ah[c], t3.v, acc1, 0, 0, 0);
    }

    // ---- epilogue: D-frag (col=lane&15, row=(lane>>4)*4+r) -> LDS reduce
#pragma unroll
    for (int r = 0; r < 4; ++r) {
      red[(((w2 * 4) + (nh * 2 + 0)) * 16 + (l4 * 4 + r)) * 16 + l15] = acc0[r];
      red[(((w2 * 4) + (nh * 2 + 1)) * 16 + (l4 * 4 + r)) * 16 + l15] = acc1[r];
    }
    __syncthreads();

    if (tid < 256) {
      const int u = tid >> 6, b = tid & 63;
      const int t = b >> 4, c16 = b & 15;
      float g3[3];
#pragma unroll
      for (int gi = 0; gi < 3; ++gi) {
        const int row = u * 3 + gi;
        float sum = bias_s[row];
#pragma unroll
        for (int ww = 0; ww < 4; ++ww)
          sum += red[((ww * 4 + t) * 16 + row) * 16 + c16];
        g3[gi] = sum;
      }
      float iv = 1.f / (1.f + expf(-g3[0]));
      float gv = tanhf(g3[1]);
      float ov = 1.f / (1.f + expf(-g3[2]));
      float hv = ov * tanhf(iv * gv);      // c stays 0 (reference bug preserved)

      const int k = j0 + u;                // h's k-index in the B matrix
      const int kb = k >> 5, ks = (k >> 3) & 3, jj = k & 7;
      unsigned char* dh = hn + kb * 8192 + b * 128 + ks * 16 + jj * 2;
      unsigned short hhv = f2bf(hv);
      unsigned short llv = f2bf(hv - bf2f(hhv));
      asm volatile("global_store_short %0, %1, off sc0 sc1"
                   :: "v"(dh), "v"((uint32_t)hhv) : "memory");
      asm volatile("global_store_short %0, %1, off sc0 sc1"
                   :: "v"(dh + 64), "v"((uint32_t)llv) : "memory");
      if (s == TT - 1) out[b * OUTW + HH + k] = hv;
    }

    // ---- atomic-free device barrier: flag store + wave-parallel uint4 poll.
    // Round 5's single atomicAdd counter serialized 256 device-scope RMWs at
    // the MALL (~18 us/step). Here: 256 independent dword stores, and wave 0
    // of every block polls all 256 slots with ONE dwordx4 load per lane.
    asm volatile("s_waitcnt vmcnt(0)" ::: "memory");   // drain h stores
    __syncthreads();
    if (wv == 0) {
      const uint32_t gen = (uint32_t)(s + 1);
      if (lane == 0) {
        unsigned int* slot = arr + bk;
        asm volatile("global_store_dword %0, %1, off sc0 sc1"
                     :: "v"(slot), "v"(gen) : "memory");
      }
      asm volatile("s_waitcnt vmcnt(0)" ::: "memory");
      const unsigned int* pl = arr + lane * 4;
      for (;;) {
        uint4 a;
        asm volatile("global_load_dwordx4 %0, %1, off sc0 sc1\n\t"
                     "s_waitcnt vmcnt(0)"
                     : "=v"(a) : "v"(pl) : "memory");
        int ok = (a.x >= gen) && (a.y >= gen) && (a.z >= gen) && (a.w >= gen);
        if (__all(ok)) break;
        __builtin_amdgcn_s_sleep(1);
      }
    }
    __syncthreads();
  }
#undef ISSUE
#undef ISSUE_H
#undef ISSUE_X
}

extern "C" void kernel_launch(void* const* d_in, const int* in_sizes, int n_in,
                              void* d_out, int out_size, void* d_ws, size_t ws_size,
                              hipStream_t stream) {
  const float* tbl   = (const float*)d_in[0];
  const float* Wih_f = (const float*)d_in[1];
  // d_in[2] = Whh_f: dead (forward h is always 0)
  const float* bih_f = (const float*)d_in[3];
  const float* bhh_f = (const float*)d_in[4];
  const float* Wih_b = (const float*)d_in[5];
  const float* Whh_b = (const float*)d_in[6];
  const float* bih_b = (const float*)d_in[7];
  const float* bhh_b = (const float*)d_in[8];
  const int*   inp   = (const int*)d_in[9];
  float* out = (float*)d_out;

  char* ws = (char*)d_ws;
  unsigned int*  arr   = (unsigned int*)ws;                  // 256 dwords = 1 KB
  unsigned char* h0ex  = (unsigned char*)(ws + 1024);        // 256 KB
  unsigned char* h1ex  = h0ex + 262144;                      // 256 KB
  float*         xT0   = (float*)(h1ex + 262144);            // 76.8 KB
  unsigned char* xfrag = (unsigned char*)(ws + 602112);      // 12.58 MB

  // zero flag array + initial h (hi/lo of 0 are 0)
  hipMemsetAsync(d_ws, 0, 1024 + 262144, stream);

  k_stage<<<dim3(TT), dim3(256), 0, stream>>>(tbl, inp, xfrag, xT0);
  k_fwd<<<dim3(256), dim3(256), 0, stream>>>(Wih_f, bih_f, bhh_f, xT0, out);

  void* args[] = { (void*)&Whh_b, (void*)&Wih_b, (void*)&bih_b, (void*)&bhh_b,
                   (void*)&xfrag, (void*)&h0ex, (void*)&h1ex, (void*)&arr, (void*)&out };
  hipLaunchCooperativeKernel((void*)k_rec, dim3(NB), dim3(NT), args, 0, stream);
}